// Round 5
// baseline (350.857 us; speedup 1.0000x reference)
//
#include <hip/hip_runtime.h>

typedef short bf16x8 __attribute__((ext_vector_type(8)));
typedef short bf16x4 __attribute__((ext_vector_type(4)));
typedef float f32x4  __attribute__((ext_vector_type(4)));
typedef unsigned int u32x2 __attribute__((ext_vector_type(2)));

#define HID 128
#define TT 32
#define HWSZ 1024
#define PX 32
#define NTHREADS 1024

__device__ __forceinline__ unsigned short f2bf(float f) {
    union { float f; unsigned int i; } v; v.f = f;
    unsigned int u = v.i;
    return (unsigned short)((u + 0x7fffu + ((u >> 16) & 1u)) >> 16);
}
__device__ __forceinline__ unsigned int cvt_pk_bf16(float lo, float hi) {
    unsigned int r;
    asm("v_cvt_pk_bf16_f32 %0, %1, %2" : "=v"(r) : "v"(lo), "v"(hi));
    return r;
}
__device__ __forceinline__ float frcp(float x) { return __builtin_amdgcn_rcpf(x); }

// lgkm-only barrier: global loads/stores stay in flight across steps.
#define BARRIER() asm volatile("s_waitcnt lgkmcnt(0)\n\ts_barrier" ::: "memory")

// Round-4 (resubmit): occupancy doubled via gate-packed A-tiles.
// 16 waves (1024 thr); wave w owns 8 hidden channels [8w, 8w+8) as TWO
// gate-packed 16-row A-tiles: tile row m = 4*dch + gate (dch=0..3, gate
// i,f,o,g). With the verified 16x16x32 D-mapping (row = 4q + r), lane (q,ln)
// holds ALL 4 GATES (r) of channel 8w + tau*4 + q at px = mt*16 + ln ->
// pointwise is lane-local. W frags: KITERS x 2 tiles x 4 VGPR = 64 VGPR
// (half of round-3) -> ~115 VGPR/wave -> 4 waves/SIMD (vs 2). Per-wave work
// halves; latency hiding doubles; no cross-wave handoff (vs round-2).
// Single accumulator (x-MFMA in-window; TLP hides it), x double-buffered with
// distance-1 register prefetch, h double-buffered, one lgkm barrier/step.
// LDS row (per px): [x s0 | x s1 | h s0 | h s1 | pad 8 shorts].
template <int CIN, bool FINAL, bool IN_LOCAL, bool OUT_LOCAL>
__global__ __launch_bounds__(NTHREADS, 4)
void lstm_layer(const void* __restrict__ in_, const float* __restrict__ W,
                const float* __restrict__ bias, void* __restrict__ y_,
                float* __restrict__ hT, float* __restrict__ cT)
{
    constexpr int K      = CIN + HID;
    constexpr int XK     = CIN / 32;           // x-part k-iters
    constexpr int HK     = HID / 32;           // h-part k-iters
    constexpr int KITERS = XK + HK;
    constexpr int HB     = 2 * CIN;            // h region base (slot s at HB + s*HID)
    constexpr int PITCH  = 2 * CIN + 2 * HID + 8;  // shorts/row; rows 16B-aligned
    constexpr int NIT2   = CIN / 64;           // fp32 staging iters (2 floats each)

    const float* inF          = (const float*)in_;
    const unsigned short* inL = (const unsigned short*)in_;
    float* yF                 = (float*)y_;
    unsigned short* yL        = (unsigned short*)y_;

    __shared__ __align__(16) unsigned short z[PX][PITCH];

    const int tid  = threadIdx.x;
    const int wave = tid >> 6;
    const int lane = tid & 63;
    const int q    = lane >> 4;
    const int ln   = lane & 15;

    const int p0  = blockIdx.x * PX;
    const int b   = p0 >> 10;
    const int hw0 = p0 & 1023;

    const long long locbase = (long long)blockIdx.x * TT * PX * HID;  // local scratch
    const long long inFbase = (long long)b * TT * CIN * HWSZ + hw0;   // fp32 [c][hw]

    const int chb = wave * 8;            // wave's first channel
    const int chq = chb + q;             // lane's channel (tile tau adds tau*4)

    // ---- preload W fragments: A-tile tau row m=ln -> W row (gate=ln&3,
    //      chan = chb + tau*4 + (ln>>2)); k-layout identical to verified code.
    bf16x8 Af[KITERS][2];
    #pragma unroll
    for (int k = 0; k < KITERS; ++k) {
        #pragma unroll
        for (int tau = 0; tau < 2; ++tau) {
            const float* wp = W + ((ln & 3) * HID + chb + tau * 4 + (ln >> 2)) * K + k * 32 + q * 8;
            bf16x8 v;
            #pragma unroll
            for (int j = 0; j < 8; ++j) v[j] = (short)f2bf(wp[j]);
            Af[k][tau] = v;
        }
    }
    // bias: element r = gate r of lane's channel (scattered scalar loads, prologue-only)
    f32x4 bsv[2];
    #pragma unroll
    for (int tau = 0; tau < 2; ++tau)
        #pragma unroll
        for (int r = 0; r < 4; ++r)
            bsv[tau][r] = bias[r * HID + chq + tau * 4];

    float* const ybase = yF + ((long long)b * TT * HID) * HWSZ + hw0;

    // ---- zero h slot0; stage x_0 -> x slot0
    *(u32x2*)&z[tid >> 5][HB + (tid & 31) * 4] = (u32x2){0u, 0u};
    if (IN_LOCAL) {
        bf16x4 v = *(const bf16x4*)(inL + locbase + tid * 4);
        *(bf16x4*)&z[tid >> 5][(tid & 31) * 4] = v;
    } else {
        #pragma unroll
        for (int it = 0; it < NIT2; ++it) {
            const int idx = tid + it * NTHREADS;
            const int pxs = idx & 31, c0 = (idx >> 5) * 2;
            const float a0 = inF[inFbase + (c0 + 0) * HWSZ + pxs];
            const float a1 = inF[inFbase + (c0 + 1) * HWSZ + pxs];
            *(unsigned int*)&z[pxs][c0] = cvt_pk_bf16(a0, a1);
        }
    }
    __syncthreads();

    float cst[2][2];          // c-state per [mt][tau]
    #pragma unroll
    for (int mt = 0; mt < 2; ++mt)
        #pragma unroll
        for (int tau = 0; tau < 2; ++tau) cst[mt][tau] = 0.0f;

    #pragma unroll 2
    for (int t = 0; t < TT; ++t) {
        const int cur = t & 1, nxt = cur ^ 1;
        const int tn = (t + 1 < TT) ? t + 1 : TT - 1;

        // ---- prefetch x_{t+1} into regs (distance-1; hidden behind this step)
        bf16x4 pfv;
        float pf[NIT2][2];
        if (IN_LOCAL) {
            pfv = *(const bf16x4*)(inL + locbase + (long long)tn * PX * HID + tid * 4);
        } else {
            #pragma unroll
            for (int it = 0; it < NIT2; ++it) {
                const int idx = tid + it * NTHREADS;
                const int pxs = idx & 31, c0 = (idx >> 5) * 2;
                pf[it][0] = inF[inFbase + (long long)tn * CIN * HWSZ + (c0 + 0) * HWSZ + pxs];
                pf[it][1] = inF[inFbase + (long long)tn * CIN * HWSZ + (c0 + 1) * HWSZ + pxs];
            }
        }

        // ---- gates = bias + Wx*x_t + Wh*h_t  (single acc set)
        f32x4 acc[2][2];
        #pragma unroll
        for (int mt = 0; mt < 2; ++mt)
            #pragma unroll
            for (int tau = 0; tau < 2; ++tau) acc[mt][tau] = bsv[tau];

        #pragma unroll
        for (int k = 0; k < XK; ++k) {
            const int koff = cur * CIN + k * 32 + q * 8;
            const bf16x8 pv0 = *(const bf16x8*)&z[ln][koff];
            const bf16x8 pv1 = *(const bf16x8*)&z[16 + ln][koff];
            acc[0][0] = __builtin_amdgcn_mfma_f32_16x16x32_bf16(Af[k][0], pv0, acc[0][0], 0, 0, 0);
            acc[0][1] = __builtin_amdgcn_mfma_f32_16x16x32_bf16(Af[k][1], pv0, acc[0][1], 0, 0, 0);
            acc[1][0] = __builtin_amdgcn_mfma_f32_16x16x32_bf16(Af[k][0], pv1, acc[1][0], 0, 0, 0);
            acc[1][1] = __builtin_amdgcn_mfma_f32_16x16x32_bf16(Af[k][1], pv1, acc[1][1], 0, 0, 0);
        }
        #pragma unroll
        for (int k = 0; k < HK; ++k) {
            const int koff = HB + cur * HID + k * 32 + q * 8;
            const bf16x8 pv0 = *(const bf16x8*)&z[ln][koff];
            const bf16x8 pv1 = *(const bf16x8*)&z[16 + ln][koff];
            acc[0][0] = __builtin_amdgcn_mfma_f32_16x16x32_bf16(Af[XK + k][0], pv0, acc[0][0], 0, 0, 0);
            acc[0][1] = __builtin_amdgcn_mfma_f32_16x16x32_bf16(Af[XK + k][1], pv0, acc[0][1], 0, 0, 0);
            acc[1][0] = __builtin_amdgcn_mfma_f32_16x16x32_bf16(Af[XK + k][0], pv1, acc[1][0], 0, 0, 0);
            acc[1][1] = __builtin_amdgcn_mfma_f32_16x16x32_bf16(Af[XK + k][1], pv1, acc[1][1], 0, 0, 0);
        }

        // ---- pointwise (lane-local gates: r = i,f,o,g), 7 trans/output
        __builtin_amdgcn_s_setprio(1);
        #pragma unroll
        for (int mt = 0; mt < 2; ++mt) {
            const int px = mt * 16 + ln;
            #pragma unroll
            for (int tau = 0; tau < 2; ++tau) {
                const int ch = chq + tau * 4;
                const float ei = __expf(-acc[mt][tau][0]);
                const float ef = __expf(-acc[mt][tau][1]);
                const float eo = __expf(-acc[mt][tau][2]);
                const float eg = __expf(-2.0f * acc[mt][tau][3]);
                const float a1 = 1.0f + ei;
                const float a2 = 1.0f + eg;
                const float a3 = 1.0f + ef;
                const float p12 = a1 * a2;
                const float num = cst[mt][tau] * p12 + (1.0f - eg) * a3;
                const float c   = num * frcp(a3 * p12);
                cst[mt][tau] = c;
                const float ec = __expf(-2.0f * c);
                const float h  = (1.0f - ec) * frcp((1.0f + eo) * (1.0f + ec));

                z[px][HB + nxt * HID + ch] = f2bf(h);
                if (FINAL || !OUT_LOCAL) {
                    ybase[((long long)t * HID + ch) * HWSZ + px] = h;
                    if (FINAL && t == TT - 1) {
                        hT[((long long)(b * HID + ch)) * HWSZ + hw0 + px] = h;
                        cT[((long long)(b * HID + ch)) * HWSZ + hw0 + px] = c;
                    }
                }
            }
        }
        __builtin_amdgcn_s_setprio(0);

        // ---- write prefetched x_{t+1} into slot nxt (not read this window)
        if (IN_LOCAL) {
            *(bf16x4*)&z[tid >> 5][nxt * CIN + (tid & 31) * 4] = pfv;
        } else {
            #pragma unroll
            for (int it = 0; it < NIT2; ++it) {
                const int idx = tid + it * NTHREADS;
                const int pxs = idx & 31, c0 = (idx >> 5) * 2;
                *(unsigned int*)&z[pxs][nxt * CIN + c0] = cvt_pk_bf16(pf[it][0], pf[it][1]);
            }
        }

        BARRIER();   // the ONLY barrier per step (lgkm-only)

        // ---- emit y_t for the next layer from just-written h (slot nxt)
        if (!FINAL && OUT_LOCAL) {
            bf16x4 hv = *(const bf16x4*)&z[tid >> 5][HB + nxt * HID + (tid & 31) * 4];
            *(bf16x4*)(yL + locbase + (long long)t * PX * HID + tid * 4) = hv;
        }
    }
}

extern "C" void kernel_launch(void* const* d_in, const int* in_sizes, int n_in,
                              void* d_out, int out_size, void* d_ws, size_t ws_size,
                              hipStream_t stream) {
    const float* x  = (const float*)d_in[0];
    const float* W0 = (const float*)d_in[1];
    const float* b0 = (const float*)d_in[2];
    const float* W1 = (const float*)d_in[3];
    const float* b1 = (const float*)d_in[4];
    float* out = (float*)d_out;

    float* y  = out;                      // [8,32,128,32,32] fp32
    float* hT = out + 33554432;           // [8,128,32,32]
    float* cT = out + 34603008;           // [8,128,32,32]

    dim3 grid(8192 / PX), block(NTHREADS);

    const size_t y0_bytes = (size_t)8 * HWSZ * TT * HID * 2;  // 67 MB block-local bf16
    if (ws_size >= y0_bytes) {
        unsigned short* y0 = (unsigned short*)d_ws;
        lstm_layer<64,  false, false, true ><<<grid, block, 0, stream>>>(x,  W0, b0, y0, nullptr, nullptr);
        lstm_layer<128, true,  true,  false><<<grid, block, 0, stream>>>(y0, W1, b1, y,  hT, cT);
    } else {
        // fallback: y0 fp32 [b][t][c][hw] in-place in the y region (same-block
        // read-before-write per element; layers are separate launches)
        lstm_layer<64,  false, false, false><<<grid, block, 0, stream>>>(x, W0, b0, y, nullptr, nullptr);
        lstm_layer<128, true,  false, false><<<grid, block, 0, stream>>>(y, W1, b1, y, hT, cT);
    }
}